// Round 7
// baseline (236.438 us; speedup 1.0000x reference)
//
#include <hip/hip_runtime.h>
#include <math.h>

// Problem constants
#define BB 512
#define RR 640
#define CC 10
#define OO 16
#define CO 160   // C*O
#define II 8
#define S_FLOATS (BB*CO)      // 81920
#define PP (16*S_FLOATS)      // floats per pass slice buffer (16 rg x 512 b x 160)

#define ZCH (RR*CO)           // zero 16B-chunk index in wf (appended by prep)
#define LSTR 165              // LDS co-stride for red (breaks pow-2 banks)
#define VSTR 164              // LDS co-stride for v tile (2-way max = free)

#define NRG 16                // r-groups: 512 blocks = 32 b-tiles x 16 rg = 2/CU
#define WVN 8                 // waves per block (512 threads)
#define RPW 5                 // r per wave (8 waves x 5 = 40 = RR/NRG)
#define STILE (16*CO)         // 2560 floats per b-tile v tile

#define XF_CHUNKS (RR*BB)         // 327680 f16x8 chunks
#define WF_CHUNKS (RR*CO*II/8)    // 102400 f16x8 chunks
#define PREP_BLOCKS ((XF_CHUNKS + WF_CHUNKS)/256 + 1)   // 1681

using f16x8 = __attribute__((ext_vector_type(8))) _Float16;  // 8 f16 (4 VGPRs)
using f32x4 = __attribute__((ext_vector_type(4))) float;     // 4 fp32

// Identity: routing logits at iter k equal u_hat . (v_0+...+v_{k-1}),
// so we carry only the accumulated v (LDS tile per block).
//
// Communication: dispatch boundaries ONLY (end-of-kernel release writeback +
// start-of-kernel acquire). R4/R5 lessons: in-kernel atomic delivery is sound
// but ~50us of MALL RMWs; sc0/sc1 write-through + counter is UNSOUND (vmcnt
// retires before MALL visibility). Dispatch-boundary coherence is free.
//
// R6 lesson (counters): wall = ~44us harness workspace-poison fill (256 MiB
// fillBufferAligned per replay, not ours) + our pipeline. So optimize the
// pipeline: passes were latency-bound at 2 waves/SIMD -> this version runs
// 8-wave blocks (4 waves/SIMD) and splits the gather across 320 threads.
//
// Structure (5 dispatches):
//   prep   : W->f16 (+zero chunk), x->f16 transposed (vectorized)
//   pass0  : uniform routing, slices -> pA
//   pass1  : gather own tile's 16 pA slices -> v0 (L2-local: a tile's blocks
//            share bid%32 -> same XCD); rg0 stores v0 -> vg; pass -> pB
//   pass2  : gather pB -> v1; vlds = vg(v0) + v1; pass -> pC
//   final  : 32 blocks gather pC -> squash -> out

// ---------- helpers ----------

// exp(a) for |a| < ~0.15 (routing logits are u.v ~ O(1e-2)):
// 3rd-order Taylor, error a^4/24 < 2e-5 — far below the 2.4e-3 threshold.
__device__ __forceinline__ float exp_small(float a) {
    float f = __builtin_fmaf(a, 0.16666667f, 0.5f);
    f = __builtin_fmaf(a, f, 1.0f);
    return __builtin_fmaf(a, f, 1.0f);
}

__device__ __forceinline__ f16x8 cvt8(const float4 lo, const float4 hi) {
    f16x8 v;
    v[0] = (_Float16)lo.x; v[1] = (_Float16)lo.y;
    v[2] = (_Float16)lo.z; v[3] = (_Float16)lo.w;
    v[4] = (_Float16)hi.x; v[5] = (_Float16)hi.y;
    v[6] = (_Float16)hi.z; v[7] = (_Float16)hi.w;
    return v;
}

// ---------- prep: W->f16 (+zero slot), x->f16 transposed ----------
// Vectorized: one f16x8 chunk per thread (2x float4 loads, 1x 16B store).
//   xf chunk t = r*BB + b holds x[b][r][0..8)   (b = t&511, r = t>>9)
//   wf chunk u holds W[8u .. 8u+8) linear
// (Mapping harness-verified in R6.)

__global__ __launch_bounds__(256) void prep(const float* __restrict__ W,
                                            const float* __restrict__ x,
                                            _Float16* __restrict__ wf,
                                            _Float16* __restrict__ xf) {
    const int t = blockIdx.x * 256 + threadIdx.x;
    if (t < XF_CHUNKS) {
        const int b = t & (BB - 1);
        const int r = t >> 9;
        const float4* xp = reinterpret_cast<const float4*>(x) + (size_t)(b * RR + r) * 2;
        const float4 lo = xp[0];
        const float4 hi = xp[1];
        reinterpret_cast<f16x8*>(xf)[t] = cvt8(lo, hi);
    } else if (t < XF_CHUNKS + WF_CHUNKS) {
        const int u = t - XF_CHUNKS;
        const float4* wp = reinterpret_cast<const float4*>(W) + (size_t)u * 2;
        const float4 lo = wp[0];
        const float4 hi = wp[1];
        reinterpret_cast<f16x8*>(wf)[u] = cvt8(lo, hi);
    } else {
        const int u = t - (XF_CHUNKS + WF_CHUNKS);   // 0..255 (last block)
        if (u < 16) wf[RR * CO * II + u] = (_Float16)0.f;  // zero chunk (A padding)
    }
}

// ---------- pass tile (device) ----------
// Wave: b_tile = 16 samples (n = lane&15), q = lane>>4; r-range r0..r0+RPW-1,
// r0 = rg*40 + wv*5 (8 waves). Routing: A-frag = W[r, c*16+m, i] on quad 0
// (q>0 -> zero chunk); B-frag = x_t[r, b0+n, :]. C layout: lane(q,n) holds
// u[b0+n, co=c*16+4q+k]. Uniform: quads K-pack 4 consecutive r's (remainder
// via zero slot); MFMA sums r directly. Block tree-reduces 8 wave-partials
// in LDS (4 write + 4 add + wave0 sums 4 rows); wave 0 stores the rg slice.

template <bool UNIFORM>
__device__ __forceinline__ void pass_tile(const _Float16* __restrict__ wf,
                                          const _Float16* __restrict__ xf,
                                          const float* __restrict__ vsrc,  // LDS, stride VSTR
                                          float* __restrict__ dst,
                                          float* __restrict__ red,   // [4*16*LSTR]
                                          int bt, int rg, int wv, int lane) {
    const int n  = lane & 15;             // b within tile; also A's m row
    const int q  = lane >> 4;             // quad
    const bool q0 = (q == 0);
    const int b0 = bt * 16;
    const int r0 = rg * (WVN * RPW) + wv * RPW;

    const f16x8* xq = reinterpret_cast<const f16x8*>(xf);  // chunk = r*BB + b
    const int4*  wq = reinterpret_cast<const int4*>(wf);   // chunk = r*CO + co

    f32x4 sacc[CC];
#pragma unroll
    for (int c = 0; c < CC; ++c) sacc[c] = (f32x4){0.f, 0.f, 0.f, 0.f};

    if (UNIFORM) {
        int rr = 0;
#pragma unroll
        for (; rr + 4 <= RPW; rr += 4) {             // full 4-r K-packed chunks
            const int r = r0 + rr + q;
            const f16x8 bfr = xq[(size_t)r * BB + b0 + n];
#pragma unroll
            for (int c = 0; c < CC; ++c) {
                const int4 a = wq[r * CO + c * 16 + n];
                sacc[c] = __builtin_amdgcn_mfma_f32_16x16x32_f16(
                    __builtin_bit_cast(f16x8, a), bfr, sacc[c], 0, 0, 0);
            }
        }
        constexpr int REM = RPW & 3;                 // remainder r's on quads<REM
        if (REM) {
            const int qq = (q < REM) ? q : 0;        // clamped (finite data)
            const int r = r0 + (RPW - REM) + qq;
            const f16x8 bfr = xq[(size_t)r * BB + b0 + n];
#pragma unroll
            for (int c = 0; c < CC; ++c) {
                const int4 a = wq[(q < REM) ? (r * CO + c * 16 + n) : ZCH];
                sacc[c] = __builtin_amdgcn_mfma_f32_16x16x32_f16(
                    __builtin_bit_cast(f16x8, a), bfr, sacc[c], 0, 0, 0);
            }
        }
    } else {
        f32x4 vv[CC];
        const float* vp = vsrc + n * VSTR;
#pragma unroll
        for (int c = 0; c < CC; ++c)
            vv[c] = *reinterpret_cast<const f32x4*>(vp + c * 16 + 4 * q);

#pragma unroll 2
        for (int rr = 0; rr < RPW; ++rr) {
            const int r = r0 + rr;
            const f16x8 bcur = xq[(size_t)r * BB + b0 + n];

            f32x4 acc[CC];
#pragma unroll
            for (int c = 0; c < CC; ++c) {
                const int4 a = wq[q0 ? (r * CO + c * 16 + n) : ZCH];
                acc[c] = __builtin_amdgcn_mfma_f32_16x16x32_f16(
                    __builtin_bit_cast(f16x8, a), bcur,
                    (f32x4){0.f, 0.f, 0.f, 0.f}, 0, 0, 0);
            }

            float e[CC];
#pragma unroll
            for (int c = 0; c < CC; ++c) {
                float t = acc[c][0] * vv[c][0] + acc[c][1] * vv[c][1]
                        + acc[c][2] * vv[c][2] + acc[c][3] * vv[c][3];
                t += __shfl_xor(t, 16);
                t += __shfl_xor(t, 32);     // full sum over o (4 quads x 4 regs)
                e[c] = exp_small(t);
            }
            const float se = (((e[0] + e[1]) + (e[2] + e[3]))
                            + ((e[4] + e[5]) + (e[6] + e[7]))) + (e[8] + e[9]);
            const float inv = __fdividef(1.0f, se);
#pragma unroll
            for (int c = 0; c < CC; ++c) {
                const float w = e[c] * inv;
#pragma unroll
                for (int k = 0; k < 4; ++k)
                    sacc[c][k] = __builtin_fmaf(w, acc[c][k], sacc[c][k]);
            }
        }
    }

    // LDS tree reduce across the block's 8 waves (4 write, 4 add, wave0 sums)
    const int cb = 4 * q;
    if (wv < 4) {
        float* dstl = red + ((wv * 16 + n) * LSTR + cb);
#pragma unroll
        for (int c = 0; c < CC; ++c)
#pragma unroll
            for (int k = 0; k < 4; ++k) dstl[c * 16 + k] = sacc[c][k];
    }
    __syncthreads();
    if (wv >= 4) {
        float* dstl = red + (((wv - 4) * 16 + n) * LSTR + cb);
#pragma unroll
        for (int c = 0; c < CC; ++c)
#pragma unroll
            for (int k = 0; k < 4; ++k) dstl[c * 16 + k] += sacc[c][k];
    }
    __syncthreads();
    if (wv == 0) {
        const float f = UNIFORM ? 0.1f : 1.0f;   // softmax(0) over C=10 -> 1/10
        const float* r1 = red + (n * LSTR + cb);
        const float* r2 = red + ((16 + n) * LSTR + cb);
        const float* r3 = red + ((32 + n) * LSTR + cb);
        const float* r4 = red + ((48 + n) * LSTR + cb);
        float* pb = dst + (size_t)rg * S_FLOATS + (size_t)(b0 + n) * CO + cb;
#pragma unroll
        for (int c = 0; c < CC; ++c) {
            f32x4 v;
#pragma unroll
            for (int k = 0; k < 4; ++k)
                v[k] = ((r1[c * 16 + k] + r2[c * 16 + k])
                      + (r3[c * 16 + k] + r4[c * 16 + k])) * f;
            *reinterpret_cast<f32x4*>(pb + c * 16) = v;
        }
    }
}

// ---------- split gather + squash (device, pass1/pass2) ----------
// 320 threads: two halves of 8 slices each; half 1 parks its partial in
// scratch (reuses red; pass_tile's red use starts after caller's sync).
// MODE 0: vlds = v; rg0 stores v -> vg.   MODE 1: vlds = vg(v0) + v.

template <int MODE>
__device__ __forceinline__ void gather_squash_split(const float* __restrict__ part,
                                                    const float* __restrict__ bias,
                                                    float* __restrict__ vlds,
                                                    float* __restrict__ vg,
                                                    float* __restrict__ scratch,
                                                    int bt, int tid, bool store_vg) {
    f32x4 s[4];
    int b = 0, c = 0;
    if (tid < 320) {
        const int half = (tid >= 160);
        const int t = tid - half * 160;
        b = t & 15;
        c = t >> 4;
        const float* pb = part + (size_t)(bt * 16 + b) * CO + c * 16;
#pragma unroll
        for (int k = 0; k < 4; ++k) s[k] = (f32x4){0.f, 0.f, 0.f, 0.f};
#pragma unroll
        for (int g = 0; g < 8; ++g) {
            const f32x4* p = reinterpret_cast<const f32x4*>(
                pb + (size_t)(half * 8 + g) * S_FLOATS);
#pragma unroll
            for (int k = 0; k < 4; ++k) s[k] += p[k];
        }
        if (half) {
            float* sc = scratch + (c * 16 + b) * 16;
#pragma unroll
            for (int k = 0; k < 4; ++k)
                *reinterpret_cast<f32x4*>(sc + k * 4) = s[k];
        }
    }
    __syncthreads();
    if (tid < 160) {
        const float* sc = scratch + (c * 16 + b) * 16;
        const f32x4* bi = reinterpret_cast<const f32x4*>(bias + c * 16);
#pragma unroll
        for (int k = 0; k < 4; ++k)
            s[k] += *reinterpret_cast<const f32x4*>(sc + k * 4) + bi[k];
        float sq = 0.f;
#pragma unroll
        for (int k = 0; k < 4; ++k)
            sq += s[k][0] * s[k][0] + s[k][1] * s[k][1]
                + s[k][2] * s[k][2] + s[k][3] * s[k][3];
        const float norm  = sqrtf(sq);
        const float scale = norm / (1.0f + sq + 1e-8f);
        f32x4* vl = reinterpret_cast<f32x4*>(vlds + b * VSTR + c * 16);
        f32x4* vgp = reinterpret_cast<f32x4*>(vg + b * CO + c * 16);
#pragma unroll
        for (int k = 0; k < 4; ++k) {
            f32x4 t;
#pragma unroll
            for (int j = 0; j < 4; ++j) t[j] = scale * s[k][j];
            if (MODE == 1) t += vgp[k];              // v0 + v1
            vl[k] = t;
            if (MODE == 0 && store_vg) vgp[k] = t;   // publish v0 (rg0 only)
        }
    }
}

// ---------- serial gather + squash -> out (final kernel) ----------

__device__ __forceinline__ void gather_out(const float* __restrict__ part,
                                           const float* __restrict__ bias,
                                           float* __restrict__ out,
                                           int bt, int tid) {
    if (tid >= 160) return;
    const int b = tid & 15;
    const int c = tid >> 4;
    const float* pb = part + (size_t)(bt * 16 + b) * CO + c * 16;
    const f32x4* bi = reinterpret_cast<const f32x4*>(bias + c * 16);
    f32x4 s[4];
#pragma unroll
    for (int k = 0; k < 4; ++k) s[k] = bi[k];
#pragma unroll 4
    for (int g = 0; g < NRG; ++g) {
        const f32x4* p = reinterpret_cast<const f32x4*>(pb + (size_t)g * S_FLOATS);
#pragma unroll
        for (int k = 0; k < 4; ++k) s[k] += p[k];
    }
    float sq = 0.f;
#pragma unroll
    for (int k = 0; k < 4; ++k)
        sq += s[k][0] * s[k][0] + s[k][1] * s[k][1]
            + s[k][2] * s[k][2] + s[k][3] * s[k][3];
    const float norm  = sqrtf(sq);
    const float scale = norm / (1.0f + sq + 1e-8f);
    f32x4* ob = reinterpret_cast<f32x4*>(out + (size_t)(bt * 16 + b) * CO + c * 16);
#pragma unroll
    for (int k = 0; k < 4; ++k) {
        f32x4 t;
#pragma unroll
        for (int j = 0; j < 4; ++j) t[j] = scale * s[k][j];
        ob[k] = t;
    }
}

// ---------- kernels ----------

__global__ __launch_bounds__(512, 4) void caps_pass0(const _Float16* __restrict__ wf,
                                                     const _Float16* __restrict__ xf,
                                                     float* __restrict__ pA) {
    __shared__ __align__(16) float red[4 * 16 * LSTR];
    const int tid = threadIdx.x;
    const int bt  = blockIdx.x & 31;
    const int rg  = blockIdx.x >> 5;
    pass_tile<true>(wf, xf, nullptr, pA, red, bt, rg, tid >> 6, tid & 63);
}

__global__ __launch_bounds__(512, 4) void caps_pass1(const _Float16* __restrict__ wf,
                                                     const _Float16* __restrict__ xf,
                                                     const float* __restrict__ pA,
                                                     float* __restrict__ pB,
                                                     float* __restrict__ vg,
                                                     const float* __restrict__ bias) {
    __shared__ __align__(16) float red[4 * 16 * LSTR];
    __shared__ __align__(16) float vlds[16 * VSTR];
    const int tid = threadIdx.x;
    const int bt  = blockIdx.x & 31;
    const int rg  = blockIdx.x >> 5;
    gather_squash_split<0>(pA, bias, vlds, vg + (size_t)bt * STILE, red,
                           bt, tid, rg == 0);              // vlds = v0
    __syncthreads();
    pass_tile<false>(wf, xf, vlds, pB, red, bt, rg, tid >> 6, tid & 63);
}

__global__ __launch_bounds__(512, 4) void caps_pass2(const _Float16* __restrict__ wf,
                                                     const _Float16* __restrict__ xf,
                                                     const float* __restrict__ pB,
                                                     float* __restrict__ pC,
                                                     float* __restrict__ vg,
                                                     const float* __restrict__ bias) {
    __shared__ __align__(16) float red[4 * 16 * LSTR];
    __shared__ __align__(16) float vlds[16 * VSTR];
    const int tid = threadIdx.x;
    const int bt  = blockIdx.x & 31;
    const int rg  = blockIdx.x >> 5;
    gather_squash_split<1>(pB, bias, vlds, vg + (size_t)bt * STILE, red,
                           bt, tid, false);                // vlds = v0 + v1
    __syncthreads();
    pass_tile<false>(wf, xf, vlds, pC, red, bt, rg, tid >> 6, tid & 63);
}

__global__ __launch_bounds__(256) void caps_final(const float* __restrict__ pC,
                                                  const float* __restrict__ bias,
                                                  float* __restrict__ out) {
    gather_out(pC, bias, out, blockIdx.x, threadIdx.x);
}

// ---------- launch ----------

extern "C" void kernel_launch(void* const* d_in, const int* in_sizes, int n_in,
                              void* d_out, int out_size, void* d_ws, size_t ws_size,
                              hipStream_t stream) {
    const float* x    = (const float*)d_in[0];   // [512,640,8]
    const float* W    = (const float*)d_in[1];   // [640,10,16,8]
    const float* bias = (const float*)d_in[2];   // [1,1,10,16]
    float* out  = (float*)d_out;                 // [512,10,16]

    // Workspace (~23.5 MiB):
    float*    pA = (float*)d_ws;                         // 5.24 MB pass-0 slices
    float*    pB = pA + (size_t)PP;                      // 5.24 MB pass-1 slices
    float*    pC = pB + (size_t)PP;                      // 5.24 MB pass-2 slices
    float*    vg = pC + (size_t)PP;                      // 328 KB v0 tiles
    _Float16* wf = (_Float16*)(vg + (size_t)32 * STILE); // 1.64 MB (+zero chunk)
    _Float16* xf = wf + (size_t)RR * CO * II + 16;       // 5.24 MB (+16: 16B align)

    prep      <<<PREP_BLOCKS, 256, 0, stream>>>(W, x, wf, xf);
    caps_pass0<<<dim3(512), 512, 0, stream>>>(wf, xf, pA);
    caps_pass1<<<dim3(512), 512, 0, stream>>>(wf, xf, pA, pB, vg, bias);
    caps_pass2<<<dim3(512), 512, 0, stream>>>(wf, xf, pB, pC, vg, bias);
    caps_final<<<dim3(32),  256, 0, stream>>>(pC, bias, out);
}

// Round 8
// 142.572 us; speedup vs baseline: 1.6584x; 1.6584x over previous
//
#include <hip/hip_runtime.h>
#include <math.h>

// Problem constants
#define BB 512
#define RR 640
#define CC 10
#define OO 16
#define CO 160   // C*O
#define II 8
#define S_FLOATS (BB*CO)      // 81920

#define ZCH (RR*CO)           // zero 16B-chunk index in wf (appended by prep)
#define LSTR 165              // LDS co-stride for red (breaks pow-2 banks)

// Occupancy-first config: 32 b-tiles x NRG r-groups = 1280 blocks = 5/CU,
// 4 waves each -> 20 waves/CU (vs 8 in R6). VGPR 84 x 5 waves/SIMD = 420
// <= 512 pool; LDS 21KB x 5 = 105KB <= 160KB. RPW=4 -> r = rg*16 + wv*4.
#define NRG 40
#define RPW 4                 // r per wave (4 waves x 4 = 16 = RR/NRG)

#define XF_CHUNKS (RR*BB)         // 327680 f16x8 chunks
#define WF_CHUNKS (RR*CO*II/8)    // 102400 f16x8 chunks
#define PREP_BLOCKS ((XF_CHUNKS + WF_CHUNKS)/256 + 1)   // 1681

using f16x8 = __attribute__((ext_vector_type(8))) _Float16;  // 8 f16 (4 VGPRs)
using f32x4 = __attribute__((ext_vector_type(4))) float;     // 4 fp32

// Identity: routing logits at iter k equal u_hat . (v_0+...+v_{k-1}),
// so we carry only the accumulated v (global vacc, read per wave).
//
// Communication: dispatch boundaries ONLY (end-of-kernel release writeback +
// start-of-kernel acquire) — the mechanism behind every verified run.
// R4: in-kernel atomic delivery sound but ~50us MALL RMW. R5: store+flag
// UNSOUND (stale lines / write-through visibility). R7: 512-thread blocks
// with tight launch_bounds spill ~130 live VGPRs -> 290MB scratch traffic.
// Hence: 7-dispatch fallback structure (the 134.3us R0 best) with the
// latency-bound passes given 2.5x more resident waves via NRG=40.
//
// Structure: prep | pass0 | squash0 | pass1 | squash1 | pass2 | squash2(out)

// ---------- helpers ----------

// exp(a) for |a| < ~0.15 (routing logits are u.v ~ O(1e-2)):
// 3rd-order Taylor, error a^4/24 < 2e-5 — far below the 2.4e-3 threshold.
__device__ __forceinline__ float exp_small(float a) {
    float f = __builtin_fmaf(a, 0.16666667f, 0.5f);
    f = __builtin_fmaf(a, f, 1.0f);
    return __builtin_fmaf(a, f, 1.0f);
}

// Full 16-lane row sum via DPP row_ror adds (o occupies lane%16).
__device__ __forceinline__ float rowsum16(float v) {
    int t;
    t = __builtin_amdgcn_update_dpp(0, __float_as_int(v), 0x128, 0xF, 0xF, true);
    v += __int_as_float(t);
    t = __builtin_amdgcn_update_dpp(0, __float_as_int(v), 0x124, 0xF, 0xF, true);
    v += __int_as_float(t);
    t = __builtin_amdgcn_update_dpp(0, __float_as_int(v), 0x122, 0xF, 0xF, true);
    v += __int_as_float(t);
    t = __builtin_amdgcn_update_dpp(0, __float_as_int(v), 0x121, 0xF, 0xF, true);
    v += __int_as_float(t);
    return v;
}

__device__ __forceinline__ f16x8 cvt8(const float4 lo, const float4 hi) {
    f16x8 v;
    v[0] = (_Float16)lo.x; v[1] = (_Float16)lo.y;
    v[2] = (_Float16)lo.z; v[3] = (_Float16)lo.w;
    v[4] = (_Float16)hi.x; v[5] = (_Float16)hi.y;
    v[6] = (_Float16)hi.z; v[7] = (_Float16)hi.w;
    return v;
}

// ---------- prep: W->f16 (+zero slot), x->f16 transposed ----------
// Vectorized (R6 harness-verified): one f16x8 chunk per thread.
//   xf chunk t = r*BB + b holds x[b][r][0..8)   (b = t&511, r = t>>9)
//   wf chunk u holds W[8u .. 8u+8) linear

__global__ __launch_bounds__(256) void prep(const float* __restrict__ W,
                                            const float* __restrict__ x,
                                            _Float16* __restrict__ wf,
                                            _Float16* __restrict__ xf) {
    const int t = blockIdx.x * 256 + threadIdx.x;
    if (t < XF_CHUNKS) {
        const int b = t & (BB - 1);
        const int r = t >> 9;
        const float4* xp = reinterpret_cast<const float4*>(x) + (size_t)(b * RR + r) * 2;
        const float4 lo = xp[0];
        const float4 hi = xp[1];
        reinterpret_cast<f16x8*>(xf)[t] = cvt8(lo, hi);
    } else if (t < XF_CHUNKS + WF_CHUNKS) {
        const int u = t - XF_CHUNKS;
        const float4* wp = reinterpret_cast<const float4*>(W) + (size_t)u * 2;
        const float4 lo = wp[0];
        const float4 hi = wp[1];
        reinterpret_cast<f16x8*>(wf)[u] = cvt8(lo, hi);
    } else {
        const int u = t - (XF_CHUNKS + WF_CHUNKS);   // 0..255 (last block)
        if (u < 16) wf[RR * CO * II + u] = (_Float16)0.f;  // zero chunk (A padding)
    }
}

// ---------- pass tile (device) ----------
// Wave: b_tile = 16 samples (n = lane&15), q = lane>>4; r-range r0..r0+RPW-1,
// r0 = rg*16 + wv*4. Routing: A-frag = W[r, c*16+m, i] on quad 0 (q>0 ->
// zero chunk, one address-cndmask); B-frag = x_t[r, b0+n, :] (k>=8 copies
// annihilated by A zeros). C layout: lane(q,n) holds u[b0+n, co=c*16+4q+k].
// Uniform: quads K-pack 4 consecutive r's (RPW=4 -> exactly one full chunk);
// MFMA sums r directly. Block tree-reduces 4 wave-partials in LDS; wave 0
// stores its rg slice with plain f32x4 stores (dispatch-boundary coherence).

template <bool UNIFORM>
__device__ __forceinline__ void pass_tile(const _Float16* __restrict__ wf,
                                          const _Float16* __restrict__ xf,
                                          const float* __restrict__ vacc,  // [512][160]
                                          float* __restrict__ dst,
                                          float* __restrict__ red,   // [2*16*LSTR]
                                          int bt, int rg, int wv, int lane) {
    const int n  = lane & 15;             // b within tile; also A's m row
    const int q  = lane >> 4;             // quad
    const bool q0 = (q == 0);
    const int b0 = bt * 16;
    const int r0 = rg * (4 * RPW) + wv * RPW;

    const f16x8* xq = reinterpret_cast<const f16x8*>(xf);  // chunk = r*BB + b
    const int4*  wq = reinterpret_cast<const int4*>(wf);   // chunk = r*CO + co

    f32x4 sacc[CC];
#pragma unroll
    for (int c = 0; c < CC; ++c) sacc[c] = (f32x4){0.f, 0.f, 0.f, 0.f};

    if (UNIFORM) {
#pragma unroll
        for (int rr = 0; rr + 4 <= RPW; rr += 4) {   // RPW=4: one full chunk
            const int r = r0 + rr + q;
            const f16x8 bfr = xq[(size_t)r * BB + b0 + n];
#pragma unroll
            for (int c = 0; c < CC; ++c) {
                const int4 a = wq[r * CO + c * 16 + n];
                sacc[c] = __builtin_amdgcn_mfma_f32_16x16x32_f16(
                    __builtin_bit_cast(f16x8, a), bfr, sacc[c], 0, 0, 0);
            }
        }
    } else {
        f32x4 vv[CC];
        const float* vp = vacc + (size_t)(b0 + n) * CO;
#pragma unroll
        for (int c = 0; c < CC; ++c)
            vv[c] = *reinterpret_cast<const f32x4*>(vp + c * 16 + 4 * q);

#pragma unroll 2
        for (int rr = 0; rr < RPW; ++rr) {
            const int r = r0 + rr;
            const f16x8 bcur = xq[(size_t)r * BB + b0 + n];

            f32x4 acc[CC];
#pragma unroll
            for (int c = 0; c < CC; ++c) {
                const int4 a = wq[q0 ? (r * CO + c * 16 + n) : ZCH];
                acc[c] = __builtin_amdgcn_mfma_f32_16x16x32_f16(
                    __builtin_bit_cast(f16x8, a), bcur,
                    (f32x4){0.f, 0.f, 0.f, 0.f}, 0, 0, 0);
            }

            float e[CC];
#pragma unroll
            for (int c = 0; c < CC; ++c) {
                float t = acc[c][0] * vv[c][0] + acc[c][1] * vv[c][1]
                        + acc[c][2] * vv[c][2] + acc[c][3] * vv[c][3];
                t += __shfl_xor(t, 16);
                t += __shfl_xor(t, 32);     // full sum over o (4 quads x 4 regs)
                e[c] = exp_small(t);
            }
            const float se = (((e[0] + e[1]) + (e[2] + e[3]))
                            + ((e[4] + e[5]) + (e[6] + e[7]))) + (e[8] + e[9]);
            const float inv = __fdividef(1.0f, se);
#pragma unroll
            for (int c = 0; c < CC; ++c) {
                const float w = e[c] * inv;
#pragma unroll
                for (int k = 0; k < 4; ++k)
                    sacc[c][k] = __builtin_fmaf(w, acc[c][k], sacc[c][k]);
            }
        }
    }

    // LDS tree reduce across the block's 4 waves
    const int cb = 4 * q;
    if (wv < 2) {
        float* dstl = red + ((wv * 16 + n) * LSTR + cb);
#pragma unroll
        for (int c = 0; c < CC; ++c)
#pragma unroll
            for (int k = 0; k < 4; ++k) dstl[c * 16 + k] = sacc[c][k];
    }
    __syncthreads();
    if (wv >= 2) {
        float* dstl = red + (((wv - 2) * 16 + n) * LSTR + cb);
#pragma unroll
        for (int c = 0; c < CC; ++c)
#pragma unroll
            for (int k = 0; k < 4; ++k) dstl[c * 16 + k] += sacc[c][k];
    }
    __syncthreads();
    if (wv == 0) {
        const float f = UNIFORM ? 0.1f : 1.0f;   // softmax(0) over C=10 -> 1/10
        const float* ra = red + (n * LSTR + cb);
        const float* rb = red + ((16 + n) * LSTR + cb);
        float* pb = dst + (size_t)rg * S_FLOATS + (size_t)(b0 + n) * CO + cb;
#pragma unroll
        for (int c = 0; c < CC; ++c) {
            f32x4 v;
#pragma unroll
            for (int k = 0; k < 4; ++k)
                v[k] = (ra[c * 16 + k] + rb[c * 16 + k]) * f;
            *reinterpret_cast<f32x4*>(pb + c * 16) = v;
        }
    }
}

// ---------- squash element (device; R0-verified) ----------
__device__ __forceinline__ void squash_elem(const float* __restrict__ part, int nsl,
                                            const float* __restrict__ bias,
                                            float* __restrict__ vacc,
                                            float* __restrict__ out,
                                            int mode, int idx) {
    const int co = idx % CO;
    float a0 = 0.f, a1 = 0.f, a2 = 0.f, a3 = 0.f;
    int s = 0;
    for (; s + 4 <= nsl; s += 4) {
        a0 += part[(size_t)s * S_FLOATS + idx];
        a1 += part[(size_t)(s + 1) * S_FLOATS + idx];
        a2 += part[(size_t)(s + 2) * S_FLOATS + idx];
        a3 += part[(size_t)(s + 3) * S_FLOATS + idx];
    }
    for (; s < nsl; ++s) a0 += part[(size_t)s * S_FLOATS + idx];
    const float val = ((a0 + a1) + (a2 + a3)) + bias[co];
    const float sq = rowsum16(val * val);            // sum over o (16-lane row)
    const float norm  = sqrtf(sq);
    const float scale = norm / (1.0f + sq + 1e-8f);
    const float v = scale * val;
    if (mode == 0)      vacc[idx] = v;
    else if (mode == 1) vacc[idx] += v;
    else                out[idx] = v;
}

// ---------- kernels ----------

template <bool UNIFORM>
__global__ __launch_bounds__(256, 2) void caps_pass_k(const _Float16* __restrict__ wf,
                                                      const _Float16* __restrict__ xf,
                                                      const float* __restrict__ vacc,
                                                      float* __restrict__ part) {
    __shared__ __align__(16) float red[2 * 16 * LSTR];
    pass_tile<UNIFORM>(wf, xf, vacc, part, red,
                       blockIdx.x, blockIdx.y, threadIdx.x >> 6, threadIdx.x & 63);
}

__global__ __launch_bounds__(256) void caps_squash_k(const float* __restrict__ part,
                                                     const float* __restrict__ bias,
                                                     float* __restrict__ vacc,
                                                     float* __restrict__ out,
                                                     int mode) {
    squash_elem(part, NRG, bias, vacc, out, mode, blockIdx.x * 256 + threadIdx.x);
}

// ---------- launch ----------

extern "C" void kernel_launch(void* const* d_in, const int* in_sizes, int n_in,
                              void* d_out, int out_size, void* d_ws, size_t ws_size,
                              hipStream_t stream) {
    const float* x    = (const float*)d_in[0];   // [512,640,8]
    const float* W    = (const float*)d_in[1];   // [640,10,16,8]
    const float* bias = (const float*)d_in[2];   // [1,1,10,16]
    float* out  = (float*)d_out;                 // [512,10,16]

    // Workspace (~20.3 MiB):
    float*    part = (float*)d_ws;                        // [40][512][160] slices
    float*    vacc = part + (size_t)NRG * S_FLOATS;       // [512][160]
    _Float16* wf   = (_Float16*)(vacc + S_FLOATS);        // 1.64 MB (+zero chunk)
    _Float16* xf   = wf + (size_t)RR * CO * II + 16;      // 5.24 MB (+16: 16B align)

    const dim3 pg(32, NRG);                  // 1280 blocks = 5/CU, 20 waves/CU
    const int sqg = S_FLOATS / 256;          // 320

    prep<<<PREP_BLOCKS, 256, 0, stream>>>(W, x, wf, xf);
    caps_pass_k<true><<<pg, 256, 0, stream>>>(wf, xf, nullptr, part);
    caps_squash_k<<<sqg, 256, 0, stream>>>(part, bias, vacc, out, 0);
    caps_pass_k<false><<<pg, 256, 0, stream>>>(wf, xf, vacc, part);
    caps_squash_k<<<sqg, 256, 0, stream>>>(part, bias, vacc, out, 1);
    caps_pass_k<false><<<pg, 256, 0, stream>>>(wf, xf, vacc, part);
    caps_squash_k<<<sqg, 256, 0, stream>>>(part, bias, vacc, out, 2);
}